// Round 4
// baseline (124.279 us; speedup 1.0000x reference)
//
#include <hip/hip_runtime.h>

// YOLO-v1 style loss on MI355X (gfx950).
// Inputs: d_in[0] = output (BATCH*S*S*30 fp32), d_in[1] = target (same).
// Outputs: d_out[0..2] = (loss, sum_iou, acc) as fp32.
//
// History:
//  R1/R2 (~175-220us, data-independent): bound by 1568 blocks x 8 atomicAdds
//    to ONE cache line -> serialized L2 RMWs. NOT load-bound.
//  R3 (kernel ~36us): persistent 512-block grid + partial stores. Left on the
//    table: 4-vs-3 tile imbalance (1568/512) + stage/compute phase
//    serialization at 2 resident blocks/CU.
//  R4: non-persistent, one 256-cell tile per block (1568 blocks), HW-scheduled
//    load balancing; per-block partial stores (no atomics); tiny finalize.

#define NACC 8
#define CELLS 256                 // cells per block (== blockDim.x)
#define TILE_FLOATS (CELLS * 30)  // 7680 floats = 30720 B per array
// partials layout in d_ws: [block][NACC]

__device__ __forceinline__ float wave_reduce_sum(float v) {
    #pragma unroll
    for (int off = 32; off > 0; off >>= 1)
        v += __shfl_down(v, off, 64);
    return v;
}

__global__ __launch_bounds__(256) void yolo_loss_kernel(
        const float* __restrict__ out,
        const float* __restrict__ tgt,
        float* __restrict__ partials, int N) {
    __shared__ float sA[TILE_FLOATS];   // output tile
    __shared__ float sB[TILE_FLOATS];   // target tile
    __shared__ float sred[4][NACC];

    const int tile0 = blockIdx.x * CELLS;
    const int cells = min(CELLS, N - tile0);
    const size_t base = (size_t)tile0 * 30;

    if (cells == CELLS) {
        // coalesced float4 staging (tile base 16B-aligned: 30720B tiles)
        const float4* gA = (const float4*)(out + base);
        const float4* gB = (const float4*)(tgt + base);
        float4* lA = (float4*)sA;
        float4* lB = (float4*)sB;
        #pragma unroll
        for (int j = 0; j < 8; j++) {
            const int f = j * 256 + threadIdx.x;
            if (f < TILE_FLOATS / 4) {
                lA[f] = gA[f];
                lB[f] = gB[f];
            }
        }
    } else {
        // tail fallback (never taken for N=401408)
        for (int f = threadIdx.x; f < cells * 30; f += 256) {
            sA[f] = out[base + f];
            sB[f] = tgt[base + f];
        }
    }
    __syncthreads();

    float v[NACC];
    #pragma unroll
    for (int k = 0; k < NACC; k++) v[k] = 0.f;

    if ((int)threadIdx.x < cells) {
        float ov[30], tv[30];
        const float2* a2 = (const float2*)(sA + threadIdx.x * 30);
        const float2* b2 = (const float2*)(sB + threadIdx.x * 30);
        #pragma unroll
        for (int k = 0; k < 15; k++) {
            const float2 xa = a2[k];
            const float2 xb = b2[k];
            ov[2 * k] = xa.x; ov[2 * k + 1] = xa.y;
            tv[2 * k] = xb.x; tv[2 * k + 1] = xb.y;
        }

        const float m = (tv[4] > 0.f) ? 1.f : 0.f;

        // target corners (xy/S +- 0.5*wh), matching reference arithmetic
        const float tx0 = tv[0] / 7.f - 0.5f * tv[2];
        const float ty0 = tv[1] / 7.f - 0.5f * tv[3];
        const float tx1 = tv[0] / 7.f + 0.5f * tv[2];
        const float ty1 = tv[1] / 7.f + 0.5f * tv[3];
        const float at  = (tx1 - tx0) * (ty1 - ty0);

        float iou[2];
        #pragma unroll
        for (int b = 0; b < 2; b++) {
            const float* pb = ov + b * 5;
            const float px0 = pb[0] / 7.f - 0.5f * pb[2];
            const float py0 = pb[1] / 7.f - 0.5f * pb[3];
            const float px1 = pb[0] / 7.f + 0.5f * pb[2];
            const float py1 = pb[1] / 7.f + 0.5f * pb[3];
            const float ap  = (px1 - px0) * (py1 - py0);
            const float ulx = fmaxf(px0, tx0), uly = fmaxf(py0, ty0);
            const float lrx = fminf(px1, tx1), lry = fminf(py1, ty1);
            const float wi  = fmaxf(lrx - ulx, 0.f);
            const float hi  = fmaxf(lry - uly, 0.f);
            const float inter = wi * hi;
            iou[b] = inter / (ap + at - inter);
        }

        // argmax, first-max tie-break: resp=1 only if strictly greater
        const int resp = (iou[1] > iou[0]) ? 1 : 0;
        const float max_iou = fmaxf(iou[0], iou[1]);
        const float min_iou = fminf(iou[0], iou[1]);
        const float* rb = ov + resp * 5;
        const float* nb = ov + (1 - resp) * 5;

        {
            const float dx = rb[0] - tv[0];
            const float dy = rb[1] - tv[1];
            const float dw = sqrtf(rb[2]) - sqrtf(tv[2]);
            const float dh = sqrtf(rb[3]) - sqrtf(tv[3]);
            v[1] = m * (dx * dx + dy * dy + dw * dw + dh * dh);
        }
        {
            const float d = rb[4] - max_iou;
            v[2] = m * d * d;
        }
        v[3] = m * nb[4] * nb[4];
        {
            const float d0 = ov[4] - tv[4];
            const float d1 = ov[9] - tv[9];
            v[4] = (1.f - m) * (d0 * d0 + d1 * d1);
        }

        // class loss + argmax accuracy (first-max semantics via strict >)
        float cls_sum = 0.f;
        int oarg = 0, targ = 0;
        float obest = ov[10], tbest = tv[10];
        #pragma unroll
        for (int c = 0; c < 20; c++) {
            const float oc = ov[10 + c], tc = tv[10 + c];
            const float d = oc - tc;
            cls_sum += d * d;
            if (oc > obest) { obest = oc; oarg = c; }
            if (tc > tbest) { tbest = tc; targ = c; }
        }
        v[5] = m * cls_sum;
        v[6] = m * min_iou;
        v[7] = (m > 0.f && oarg == targ) ? 1.f : 0.f;
        v[0] = m;
    }

    // block reduce 8 sums, then ONE plain store set per block (no atomics)
    const int lane = threadIdx.x & 63;
    const int wid  = threadIdx.x >> 6;
    #pragma unroll
    for (int k = 0; k < NACC; k++) v[k] = wave_reduce_sum(v[k]);
    if (lane == 0) {
        #pragma unroll
        for (int k = 0; k < NACC; k++) sred[wid][k] = v[k];
    }
    __syncthreads();
    if (threadIdx.x < NACC) {
        const int k = threadIdx.x;
        partials[blockIdx.x * NACC + k] =
            sred[0][k] + sred[1][k] + sred[2][k] + sred[3][k];
    }
}

__global__ __launch_bounds__(256) void yolo_finalize_kernel(
        const float* __restrict__ partials,
        float* __restrict__ res, int N, int nBlocks) {
    __shared__ float sred[4][NACC];
    float v[NACC];
    #pragma unroll
    for (int k = 0; k < NACC; k++) v[k] = 0.f;
    for (int b = threadIdx.x; b < nBlocks; b += 256) {
        #pragma unroll
        for (int k = 0; k < NACC; k++) v[k] += partials[b * NACC + k];
    }
    const int lane = threadIdx.x & 63;
    const int wid  = threadIdx.x >> 6;
    #pragma unroll
    for (int k = 0; k < NACC; k++) v[k] = wave_reduce_sum(v[k]);
    if (lane == 0) {
        #pragma unroll
        for (int k = 0; k < NACC; k++) sred[wid][k] = v[k];
    }
    __syncthreads();
    if (threadIdx.x == 0) {
        float acc[NACC];
        #pragma unroll
        for (int k = 0; k < NACC; k++)
            acc[k] = sred[0][k] + sred[1][k] + sred[2][k] + sred[3][k];
        const float n_obj   = acc[0];
        const float n_noobj = (float)N - n_obj;
        const float contain     = acc[1] / (2.f * n_obj);
        const float obj_loss    = acc[2] / n_obj;
        const float not_contain = acc[3] / n_obj;
        const float noobj_loss  = acc[4] / (2.f * n_noobj);
        const float class_loss  = acc[5] / (n_obj * 20.f);
        res[0] = 5.f * contain + obj_loss
               + 0.5f * (noobj_loss + not_contain) + class_loss;
        res[1] = acc[6];
        res[2] = acc[7];
    }
}

extern "C" void kernel_launch(void* const* d_in, const int* in_sizes, int n_in,
                              void* d_out, int out_size, void* d_ws, size_t ws_size,
                              hipStream_t stream) {
    const float* out_p = (const float*)d_in[0];
    const float* tgt_p = (const float*)d_in[1];
    float* ws  = (float*)d_ws;   // nBlocks*8 partial sums
    float* res = (float*)d_out;
    const int N = in_sizes[0] / 30;       // 8192*7*7 = 401408 cells
    const int nBlocks = (N + CELLS - 1) / CELLS;  // 1568

    yolo_loss_kernel<<<nBlocks, 256, 0, stream>>>(out_p, tgt_p, ws, N);
    yolo_finalize_kernel<<<1, 256, 0, stream>>>(ws, res, N, nBlocks);
}

// Round 6
// 124.027 us; speedup vs baseline: 1.0020x; 1.0020x over previous
//
#include <hip/hip_runtime.h>

// YOLO-v1 style loss on MI355X (gfx950).
// Inputs: d_in[0] = output (BATCH*S*S*30 fp32), d_in[1] = target (same).
// Outputs: d_out[0..2] = (loss, sum_iou, acc) as fp32.
//
// History:
//  R1/R2 (~175-220us, data-independent): 1568 blocks x 8 atomicAdds to ONE
//    cache line -> serialized L2 RMWs.
//  R3/R4 (kernel ~41us, 2.35 TB/s effective): barrier-coupled stage/compute
//    phases at 2 blocks/CU -> ~50% memory-pipe duty cycle.
//  R5 FAILED (NaN): global_load_lds width=12 LDS lane-stride unverified ->
//    corrupted slices. Lesson: only the 16B variant is HW-verified (m97).
//  R6: barrier-free per-WAVE private LDS slices, staged with proven
//    float4 -> ds_write_b128 path. No __syncthreads in the loss kernel;
//    same-wave LDS write->read needs none (DS ops complete in issue order,
//    compiler inserts lgkmcnt waits). 8 independent waves/CU overlap
//    staging and compute.

#define NACC 8
#define WAVES_PER_BLOCK 4
#define WAVE_CELLS 64
#define SLICE_FLOATS (WAVE_CELLS * 30)   // 1920 floats = 7680 B per array
#define SLICE_F4     (SLICE_FLOATS / 4)  // 480 float4

__device__ __forceinline__ float wave_reduce_sum(float v) {
    #pragma unroll
    for (int off = 32; off > 0; off >>= 1)
        v += __shfl_down(v, off, 64);
    return v;
}

__global__ __launch_bounds__(256) void yolo_loss_kernel(
        const float* __restrict__ out,
        const float* __restrict__ tgt,
        float* __restrict__ partials, int N) {
    // per-wave private slices; no cross-wave sharing -> no barriers
    __shared__ float sA[WAVES_PER_BLOCK][SLICE_FLOATS];
    __shared__ float sB[WAVES_PER_BLOCK][SLICE_FLOATS];

    const int wid  = threadIdx.x >> 6;
    const int lane = threadIdx.x & 63;
    const int row  = blockIdx.x * WAVES_PER_BLOCK + wid;
    const int cell0 = row * WAVE_CELLS;

    float* lA = sA[wid];
    float* lB = sB[wid];

    float v[NACC];
    #pragma unroll
    for (int k = 0; k < NACC; k++) v[k] = 0.f;

    const int cells = min(WAVE_CELLS, N - cell0);
    if (cells == WAVE_CELLS) {
        // coalesced float4 staging of this wave's 7680B x2 slice
        // (slice base is 7680B-aligned -> 16B ok)
        const float4* gA = (const float4*)(out + (size_t)cell0 * 30);
        const float4* gB = (const float4*)(tgt + (size_t)cell0 * 30);
        float4* lA4 = (float4*)lA;
        float4* lB4 = (float4*)lB;
        #pragma unroll
        for (int j = 0; j < 8; j++) {
            const int f = j * 64 + lane;   // 480 float4s: last iter half-wave
            if (f < SLICE_F4) {
                lA4[f] = gA[f];
                lB4[f] = gB[f];
            }
        }
    } else if (cells > 0) {
        // tail fallback (never taken for N=401408)
        for (int f = lane; f < cells * 30; f += 64) {
            lA[f] = out[(size_t)cell0 * 30 + f];
            lB[f] = tgt[(size_t)cell0 * 30 + f];
        }
    }
    // no barrier: same-wave ds_write -> ds_read; compiler orders + waits

    if (lane < cells) {
        float ov[30], tv[30];
        const float2* a2 = (const float2*)(lA + lane * 30);
        const float2* b2 = (const float2*)(lB + lane * 30);
        #pragma unroll
        for (int k = 0; k < 15; k++) {
            const float2 xa = a2[k];
            const float2 xb = b2[k];
            ov[2 * k] = xa.x; ov[2 * k + 1] = xa.y;
            tv[2 * k] = xb.x; tv[2 * k + 1] = xb.y;
        }

        const float m = (tv[4] > 0.f) ? 1.f : 0.f;

        // target corners (xy/S +- 0.5*wh), matching reference arithmetic
        const float tx0 = tv[0] / 7.f - 0.5f * tv[2];
        const float ty0 = tv[1] / 7.f - 0.5f * tv[3];
        const float tx1 = tv[0] / 7.f + 0.5f * tv[2];
        const float ty1 = tv[1] / 7.f + 0.5f * tv[3];
        const float at  = (tx1 - tx0) * (ty1 - ty0);

        float iou[2];
        #pragma unroll
        for (int b = 0; b < 2; b++) {
            const float* pb = ov + b * 5;
            const float px0 = pb[0] / 7.f - 0.5f * pb[2];
            const float py0 = pb[1] / 7.f - 0.5f * pb[3];
            const float px1 = pb[0] / 7.f + 0.5f * pb[2];
            const float py1 = pb[1] / 7.f + 0.5f * pb[3];
            const float ap  = (px1 - px0) * (py1 - py0);
            const float ulx = fmaxf(px0, tx0), uly = fmaxf(py0, ty0);
            const float lrx = fminf(px1, tx1), lry = fminf(py1, ty1);
            const float wi  = fmaxf(lrx - ulx, 0.f);
            const float hi  = fmaxf(lry - uly, 0.f);
            const float inter = wi * hi;
            iou[b] = inter / (ap + at - inter);
        }

        // argmax, first-max tie-break: resp=1 only if strictly greater
        const int resp = (iou[1] > iou[0]) ? 1 : 0;
        const float max_iou = fmaxf(iou[0], iou[1]);
        const float min_iou = fminf(iou[0], iou[1]);
        const float* rb = ov + resp * 5;
        const float* nb = ov + (1 - resp) * 5;

        {
            const float dx = rb[0] - tv[0];
            const float dy = rb[1] - tv[1];
            const float dw = sqrtf(rb[2]) - sqrtf(tv[2]);
            const float dh = sqrtf(rb[3]) - sqrtf(tv[3]);
            v[1] = m * (dx * dx + dy * dy + dw * dw + dh * dh);
        }
        {
            const float d = rb[4] - max_iou;
            v[2] = m * d * d;
        }
        v[3] = m * nb[4] * nb[4];
        {
            const float d0 = ov[4] - tv[4];
            const float d1 = ov[9] - tv[9];
            v[4] = (1.f - m) * (d0 * d0 + d1 * d1);
        }

        // class loss + argmax accuracy (first-max semantics via strict >)
        float cls_sum = 0.f;
        int oarg = 0, targ = 0;
        float obest = ov[10], tbest = tv[10];
        #pragma unroll
        for (int c = 0; c < 20; c++) {
            const float oc = ov[10 + c], tc = tv[10 + c];
            const float d = oc - tc;
            cls_sum += d * d;
            if (oc > obest) { obest = oc; oarg = c; }
            if (tc > tbest) { tbest = tc; targ = c; }
        }
        v[5] = m * cls_sum;
        v[6] = m * min_iou;
        v[7] = (m > 0.f && oarg == targ) ? 1.f : 0.f;
        v[0] = m;
    }

    // wave-level reduce, per-wave partial store. No block reduction.
    #pragma unroll
    for (int k = 0; k < NACC; k++) v[k] = wave_reduce_sum(v[k]);
    if (lane == 0) {
        float* p = partials + (size_t)row * NACC;
        #pragma unroll
        for (int k = 0; k < NACC; k++) p[k] = v[k];
    }
}

__global__ __launch_bounds__(256) void yolo_finalize_kernel(
        const float* __restrict__ partials,
        float* __restrict__ res, int N, int nRows) {
    __shared__ float sred[4][NACC];
    float v[NACC];
    #pragma unroll
    for (int k = 0; k < NACC; k++) v[k] = 0.f;
    // rows are 8 floats = 2 float4
    const float4* p4 = (const float4*)partials;
    for (int b = threadIdx.x; b < nRows; b += 256) {
        const float4 x = p4[b * 2 + 0];
        const float4 y = p4[b * 2 + 1];
        v[0] += x.x; v[1] += x.y; v[2] += x.z; v[3] += x.w;
        v[4] += y.x; v[5] += y.y; v[6] += y.z; v[7] += y.w;
    }
    const int lane = threadIdx.x & 63;
    const int wid  = threadIdx.x >> 6;
    #pragma unroll
    for (int k = 0; k < NACC; k++) v[k] = wave_reduce_sum(v[k]);
    if (lane == 0) {
        #pragma unroll
        for (int k = 0; k < NACC; k++) sred[wid][k] = v[k];
    }
    __syncthreads();
    if (threadIdx.x == 0) {
        float acc[NACC];
        #pragma unroll
        for (int k = 0; k < NACC; k++)
            acc[k] = sred[0][k] + sred[1][k] + sred[2][k] + sred[3][k];
        const float n_obj   = acc[0];
        const float n_noobj = (float)N - n_obj;
        const float contain     = acc[1] / (2.f * n_obj);
        const float obj_loss    = acc[2] / n_obj;
        const float not_contain = acc[3] / n_obj;
        const float noobj_loss  = acc[4] / (2.f * n_noobj);
        const float class_loss  = acc[5] / (n_obj * 20.f);
        res[0] = 5.f * contain + obj_loss
               + 0.5f * (noobj_loss + not_contain) + class_loss;
        res[1] = acc[6];
        res[2] = acc[7];
    }
}

extern "C" void kernel_launch(void* const* d_in, const int* in_sizes, int n_in,
                              void* d_out, int out_size, void* d_ws, size_t ws_size,
                              hipStream_t stream) {
    const float* out_p = (const float*)d_in[0];
    const float* tgt_p = (const float*)d_in[1];
    float* ws  = (float*)d_ws;   // nRows * 8 partial sums
    float* res = (float*)d_out;
    const int N = in_sizes[0] / 30;                          // 401408 cells
    const int cellsPerBlock = WAVES_PER_BLOCK * WAVE_CELLS;  // 256
    const int nBlocks = (N + cellsPerBlock - 1) / cellsPerBlock;  // 1568
    const int nRows = nBlocks * WAVES_PER_BLOCK;             // 6272

    yolo_loss_kernel<<<nBlocks, 256, 0, stream>>>(out_p, tgt_p, ws, N);
    yolo_finalize_kernel<<<1, 256, 0, stream>>>(ws, res, N, nRows);
}